// Round 4
// baseline (726.938 us; speedup 1.0000x reference)
//
#include <hip/hip_runtime.h>
#include <hip/hip_cooperative_groups.h>
#include <cstdint>
#include <cstddef>

namespace cg = cooperative_groups;

// Problem constants: B=32, LQ=LA=1024, H=512
#define NB   32
#define LQA  1024   // LQ == LA
#define HD   512

typedef __attribute__((ext_vector_type(4))) float  f32x4;
typedef __attribute__((ext_vector_type(8))) short  s16x8;   // 8 bf16 (4 VGPRs) MFMA frag
typedef __attribute__((ext_vector_type(4))) unsigned short u16x4;

static __device__ __forceinline__ unsigned short f2bf(float f) {
  unsigned int u = __builtin_bit_cast(unsigned int, f);
  u += 0x7fffu + ((u >> 16) & 1u);      // RNE
  return (unsigned short)(u >> 16);
}
static __device__ __forceinline__ float bf2f(unsigned short h) {
  unsigned int u = ((unsigned int)h) << 16;
  return __builtin_bit_cast(float, u);
}
static __device__ __forceinline__ u16x4 cvt4(f32x4 v) {
  u16x4 r;
  r.x = f2bf(v.x); r.y = f2bf(v.y); r.z = f2bf(v.z); r.w = f2bf(v.w);
  return r;
}

// async global->LDS, 16B per lane; lds base must be wave-uniform (HW scatters
// lane i at base + i*16)
typedef __attribute__((address_space(1))) const void gas_void;
typedef __attribute__((address_space(3))) void las_void;
static __device__ __forceinline__ void gload_lds16(const void* g, void* l) {
  __builtin_amdgcn_global_load_lds((gas_void*)g, (las_void*)l, 16, 0, 0);
}

// ---------------------------------------------------------------------------
// Mega-kernel: the whole pipeline in ONE cooperative dispatch.
//   phase 0: zero atomic accumulators (sums/qsum/asum, 384 KB contiguous)
//   phase 1: prep  (fp32 copy to concat-left, bf16 row-major + transposed
//                   copies, fused per-h column sums)          [8192 v-tiles]
//   phase 2: scores E = qm*am*exp(temp*q.a), E and E^T, fused row/col sums
//                                                             [2048 v-tiles]
//   phase 3: agg   out_right = f(sum) . (E @ Bt) + add-term   [ 512 v-blocks]
// grid: 256 blocks x 512 threads, 1 block/CU (LDS 120 KB), grid.sync between
// phases. Phases 1/2 run as two independent 256-thread groups per block
// sharing block barriers (identical barrier sequences in both groups).
// ---------------------------------------------------------------------------
__global__ __launch_bounds__(512, 2) void k_mega(
    const float* __restrict__ qsrc, const float* __restrict__ asrc,
    const int* __restrict__ qmask, const int* __restrict__ amask,
    const float* __restrict__ temp_p,
    float* __restrict__ out0, float* __restrict__ out1,
    unsigned short* __restrict__ E,    unsigned short* __restrict__ ET,
    unsigned short* __restrict__ qT,   unsigned short* __restrict__ aT,
    unsigned short* __restrict__ qb16, unsigned short* __restrict__ ab16,
    float* __restrict__ sums,          // [2][NB*LQA] rowsumE | colsumE
    float* __restrict__ qsum, float* __restrict__ asum)  // [NB*HD] each
{
  cg::grid_group grid = cg::this_grid();
  const int r = blockIdx.x;     // 0..255 (1 block per CU)
  const int t = threadIdx.x;    // 0..511

  // 120 KB shared, reused by every phase
  __shared__ __align__(16) unsigned short lds[3 * 20480];

  // ------------------------- phase 0: zero accumulators -------------------
  {
    // sums(65536) + qsum(16384) + asum(16384) = 98304 contiguous floats
    const int idx = r * 512 + t;
    if (idx < 2 * NB * LQA + 2 * NB * HD) sums[idx] = 0.f;
  }
  grid.sync();

  // ------------------------- phase 1: prep --------------------------------
  {
    const int g  = t >> 8;       // 0..1 (256-thread group)
    const int tt = t & 255;
    unsigned short* T = lds + g * (64 * 68);

    for (int it = 0; it < 16; ++it) {
      const int v   = it * 512 + r * 2 + g;    // 0..8191
      const int bz  = v >> 7;                  // 0..63
      const int isA = bz >> 5;
      const int b   = bz & 31;
      const int q0  = ((v >> 3) & 15) * 64;
      const int h0  = (v & 7) * 64;

      const float* src     = isA ? asrc : qsrc;
      float* out_left      = isA ? out1 : out0;
      unsigned short* dstT = isA ? aT : qT;
      unsigned short* dstN = isA ? ab16 : qb16;
      float* csum          = isA ? asum : qsum;

      const float* sb = src + (size_t)b * LQA * HD;
      float* ob       = out_left + (size_t)b * LQA * 1024;
      unsigned short* db  = dstT + (size_t)b * HD * LQA;
      unsigned short* dbn = dstN + (size_t)b * LQA * HD;

#pragma unroll
      for (int j = 0; j < 4; ++j) {
        int f = tt + 256 * j;
        int rr = f >> 4;           // 0..63 (q-local)
        int c  = (f & 15) * 4;     // 0..60 (h-local)
        f32x4 vv = *(const f32x4*)(sb + (size_t)(q0 + rr) * HD + h0 + c);
        *(f32x4*)(ob + (size_t)(q0 + rr) * 1024 + h0 + c) = vv;  // concat left
        u16x4 cv = cvt4(vv);
        *(u16x4*)&dbn[(size_t)(q0 + rr) * HD + h0 + c] = cv;     // row-major
        *(u16x4*)&T[rr * 68 + c] = cv;
      }
      __syncthreads();
#pragma unroll
      for (int j = 0; j < 4; ++j) {
        int f = tt + 256 * j;
        int orow = f >> 4;         // 0..63 (h-local); 16 lanes share it
        int c = (f & 15) * 4;      // 0..60 (q-local)
        u16x4 vv;
        vv.x = T[(c + 0) * 68 + orow];
        vv.y = T[(c + 1) * 68 + orow];
        vv.z = T[(c + 2) * 68 + orow];
        vv.w = T[(c + 3) * 68 + orow];
        *(u16x4*)&db[(size_t)(h0 + orow) * LQA + q0 + c] = vv;
        // fused column sum over this 16-lane group's 64 q-cols of row h
        float s = bf2f(vv.x) + bf2f(vv.y) + bf2f(vv.z) + bf2f(vv.w);
        s += __shfl_xor(s, 1); s += __shfl_xor(s, 2);
        s += __shfl_xor(s, 4); s += __shfl_xor(s, 8);
        if ((tt & 15) == 0)
          atomicAdd(&csum[(size_t)b * HD + h0 + orow], s);
      }
      __syncthreads();   // protect T before next virtual tile overwrites it
    }
  }
  grid.sync();

  // ------------------------- phase 2: scores ------------------------------
  {
    const int g  = t >> 8;
    const int tt = t & 255;
    unsigned short* smem = lds + g * 16896;   // 33.8 KB per group
    unsigned short* As = smem;                // [128][64]
    unsigned short* Bs = smem + 8192;         // [128][64]

    const int lane = tt & 63;
    const int w    = tt >> 6;
    const int moff = (w & 1) * 64;
    const int noff = (w >> 1) * 64;
    const int lrow = lane & 15;
    const int quad = lane >> 4;
    const float temp = temp_p[0];

    for (int it = 0; it < 4; ++it) {
      const int flat = it * 512 + r * 2 + g;   // 0..2047
      const int xcd  = flat & 7;
      const int i5   = flat >> 3;
      const int b    = (i5 >> 6) * 8 + xcd;
      const int tile = i5 & 63;
      const int m0 = (tile & 7) * 128;
      const int n0 = (tile >> 3) * 128;

      const unsigned short* qb = qb16 + (size_t)b * LQA * HD;
      const unsigned short* ab = ab16 + (size_t)b * LQA * HD;
      const unsigned short* qg = qb + (size_t)(m0 + (tt >> 3)) * HD + (tt & 7) * 8;
      const unsigned short* ag = ab + (size_t)(n0 + (tt >> 3)) * HD + (tt & 7) * 8;

      f32x4 acc[4][4];
#pragma unroll
      for (int i = 0; i < 4; ++i)
#pragma unroll
        for (int j = 0; j < 4; ++j) acc[i][j] = (f32x4)0.f;

      for (int kt = 0; kt < HD / 64; ++kt) {
        const int ko = kt * 64;
#pragma unroll
        for (int p = 0; p < 4; ++p) {
          gload_lds16(qg + ko + p * 32 * HD, As + (w + 4 * p) * 512);
          gload_lds16(ag + ko + p * 32 * HD, Bs + (w + 4 * p) * 512);
        }
        __syncthreads();
#pragma unroll
        for (int ks = 0; ks < 2; ++ks) {
          s16x8 af[4], bfr[4];
#pragma unroll
          for (int i = 0; i < 4; ++i) {
            af[i]  = *(const s16x8*)&As[(moff + i * 16 + lrow) * 64 + ks * 32 + quad * 8];
            bfr[i] = *(const s16x8*)&Bs[(noff + i * 16 + lrow) * 64 + ks * 32 + quad * 8];
          }
#pragma unroll
          for (int i = 0; i < 4; ++i)
#pragma unroll
            for (int j = 0; j < 4; ++j)
              acc[i][j] = __builtin_amdgcn_mfma_f32_16x16x32_bf16(af[i], bfr[j], acc[i][j], 0, 0, 0);
        }
        __syncthreads();
      }

      // Epilogue: temp/mask/exp -> Cs (bf16), partial sums, E / E^T writes.
      unsigned short* Cs = smem;   // [128][132]
      const int* qmb = qmask + b * LQA;
      const int* amb = amask + b * LQA;

      float rowp[4][4];
      float colp[4];
#pragma unroll
      for (int i = 0; i < 4; ++i)
#pragma unroll
        for (int rr = 0; rr < 4; ++rr) rowp[i][rr] = 0.f;
#pragma unroll
      for (int j = 0; j < 4; ++j) colp[j] = 0.f;

#pragma unroll
      for (int i = 0; i < 4; ++i) {
#pragma unroll
        for (int j = 0; j < 4; ++j) {
          int ncol = noff + j * 16 + lrow;
          float am = (amb[n0 + ncol] != 0) ? 1.f : 0.f;
#pragma unroll
          for (int rr = 0; rr < 4; ++rr) {
            int mrow = moff + i * 16 + quad * 4 + rr;
            float qm = (qmb[m0 + mrow] != 0) ? 1.f : 0.f;
            float e = __expf(acc[i][j][rr] * temp) * am * qm;
            unsigned short eb = f2bf(e);
            float er = bf2f(eb);             // sum the ROUNDED value (matches E)
            Cs[mrow * 132 + ncol] = eb;
            rowp[i][rr] += er;
            colp[j] += er;
          }
        }
      }

      // row sums: 16-lane butterfly, one atomic per row per wave.
#pragma unroll
      for (int i = 0; i < 4; ++i)
#pragma unroll
        for (int rr = 0; rr < 4; ++rr) {
          float v = rowp[i][rr];
          v += __shfl_xor(v, 1); v += __shfl_xor(v, 2);
          v += __shfl_xor(v, 4); v += __shfl_xor(v, 8);
          if (lrow == 0)
            atomicAdd(&sums[(size_t)b * LQA + m0 + moff + i * 16 + quad * 4 + rr], v);
        }
      // col sums: quads hold disjoint 16-row partials of the same col.
#pragma unroll
      for (int j = 0; j < 4; ++j) {
        float v = colp[j];
        v += __shfl_xor(v, 16); v += __shfl_xor(v, 32);
        if (quad == 0)
          atomicAdd(&sums[(size_t)NB * LQA + (size_t)b * LQA + n0 + noff + j * 16 + lrow], v);
      }

      __syncthreads();
      const size_t Ebase = (size_t)b * LQA * LQA;
#pragma unroll
      for (int jj = 0; jj < 16; ++jj) {
        int f = tt + 256 * jj;
        int row = f >> 5;
        int c = (f & 31) * 4;
        u16x4 v = *(const u16x4*)&Cs[row * 132 + c];
        *(u16x4*)&E[Ebase + (size_t)(m0 + row) * LQA + n0 + c] = v;
      }
#pragma unroll
      for (int jj = 0; jj < 16; ++jj) {
        int f = tt + 256 * jj;
        int orow = f >> 5;           // a-local
        int c = (f & 31) * 4;        // q-local
        u16x4 v;
        v.x = Cs[(c + 0) * 132 + orow];
        v.y = Cs[(c + 1) * 132 + orow];
        v.z = Cs[(c + 2) * 132 + orow];
        v.w = Cs[(c + 3) * 132 + orow];
        *(u16x4*)&ET[Ebase + (size_t)(n0 + orow) * LQA + m0 + c] = v;
      }
      __syncthreads();   // protect smem before next virtual tile stages
    }
  }
  grid.sync();

  // ------------------------- phase 3: agg ---------------------------------
  {
    const int lane = t & 63;
    const int w    = t >> 6;
    const int wr   = w >> 2;
    const int wc   = w & 3;
    const int lrow = lane & 15;
    const int quad = lane >> 4;

    for (int it = 0; it < 2; ++it) {
      const int blk  = it * 256 + r;             // 0..511
      const int L    = (blk & 7) * 64 + (blk >> 3);
      const int half = L >> 8;
      const int rem  = L & 255;
      const int b    = rem >> 3;
      const int m0   = (rem & 7) * 128;

      const unsigned short* Emat = half ? ET : E;
      const unsigned short* Bt   = half ? qT : aT;
      const float* srow = sums + (size_t)half * NB * LQA + (size_t)b * LQA;
      const float* bsp  = (half ? qsum : asum) + (size_t)b * HD;
      float* ob = (half ? out1 : out0) + (size_t)b * LQA * 1024;

      const unsigned short* Eb = Emat + (size_t)b * LQA * LQA;
      const unsigned short* Bb = Bt + (size_t)b * HD * LQA;

      const unsigned short* agp = Eb + (size_t)(m0 + (t >> 2)) * LQA + (t & 3) * 8;
      const unsigned short* bgp[4];
#pragma unroll
      for (int p = 0; p < 4; ++p)
        bgp[p] = Bb + (size_t)(128 * p + (t >> 2)) * LQA + (t & 3) * 8;
      const int ldsA = w * 512;
      const int ldsB = 4096 + w * 512;

#define STAGE(kt, buf)                                                     \
      do {                                                                 \
        unsigned short* bp_ = lds + (buf) * 20480;                         \
        const int ko_ = (kt) * 32;                                         \
        gload_lds16(agp + ko_, bp_ + ldsA);                                \
        gload_lds16(bgp[0] + ko_, bp_ + ldsB);                             \
        gload_lds16(bgp[1] + ko_, bp_ + ldsB + 4096);                      \
        gload_lds16(bgp[2] + ko_, bp_ + ldsB + 8192);                      \
        gload_lds16(bgp[3] + ko_, bp_ + ldsB + 12288);                     \
      } while (0)

      f32x4 acc[4][8];
#pragma unroll
      for (int i = 0; i < 4; ++i)
#pragma unroll
        for (int j = 0; j < 8; ++j) acc[i][j] = (f32x4)0.f;

      STAGE(0, 0); STAGE(1, 1); STAGE(2, 2);

      int cur = 0;
      for (int k = 0; k < 32; ++k) {
        if (k <= 29)      asm volatile("s_waitcnt vmcnt(10)");
        else if (k == 30) asm volatile("s_waitcnt vmcnt(5)");
        else              asm volatile("s_waitcnt vmcnt(0)");
        __builtin_amdgcn_sched_barrier(0);
        __builtin_amdgcn_s_barrier();
        __builtin_amdgcn_sched_barrier(0);

        const unsigned short* As = lds + cur * 20480;
        const unsigned short* Bs = As + 4096;
        s16x8 bfr[8];
#pragma unroll
        for (int j = 0; j < 8; ++j)
          bfr[j] = *(const s16x8*)&Bs[(wc * 128 + j * 16 + lrow) * 32 + quad * 8];
#pragma unroll
        for (int i = 0; i < 4; ++i) {
          s16x8 af = *(const s16x8*)&As[(wr * 64 + i * 16 + lrow) * 32 + quad * 8];
#pragma unroll
          for (int j = 0; j < 8; ++j)
            acc[i][j] = __builtin_amdgcn_mfma_f32_16x16x32_bf16(af, bfr[j], acc[i][j], 0, 0, 0);
        }

        asm volatile("s_waitcnt lgkmcnt(0)");
        __builtin_amdgcn_sched_barrier(0);
        __builtin_amdgcn_s_barrier();
        if (k + 3 < 32) STAGE(k + 3, cur);
        cur = (cur == 2) ? 0 : cur + 1;
      }
#undef STAGE

      // Epilogue: inline stats (inv/add from raw sum) + uniform-row term.
      float bcol[8];
#pragma unroll
      for (int j = 0; j < 8; ++j) bcol[j] = bsp[wc * 128 + j * 16 + lrow];
#pragma unroll
      for (int i = 0; i < 4; ++i) {
#pragma unroll
        for (int rr = 0; rr < 4; ++rr) {
          int mrow = wr * 64 + i * 16 + quad * 4 + rr;
          float s = srow[m0 + mrow];
          float inv = (s > 0.f) ? 1.f / s : 0.f;
          float add = (s > 0.f) ? 0.f : (1.f / 1024.f);
#pragma unroll
          for (int j = 0; j < 8; ++j) {
            int ncol = wc * 128 + j * 16 + lrow;
            ob[(size_t)(m0 + mrow) * 1024 + 512 + ncol] =
                inv * acc[i][rr == 0 ? j : j][rr] + add * bcol[j];
          }
        }
      }
    }
  }
}

// ---------------------------------------------------------------------------
extern "C" void kernel_launch(void* const* d_in, const int* in_sizes, int n_in,
                              void* d_out, int out_size, void* d_ws, size_t ws_size,
                              hipStream_t stream) {
  (void)in_sizes; (void)n_in; (void)out_size; (void)ws_size;
  const float* q    = (const float*)d_in[0];
  const float* a    = (const float*)d_in[1];
  const int*   qm   = (const int*)d_in[2];
  const int*   am   = (const int*)d_in[3];
  const float* temp = (const float*)d_in[4];

  float* out0 = (float*)d_out;                         // [NB][LQA][1024] concat(q, q_s)
  float* out1 = out0 + (size_t)NB * LQA * 1024;        // [NB][LQA][1024] concat(a, a_s)

  char* ws = (char*)d_ws;
  const size_t MB = 1024ull * 1024ull;
  unsigned short* E    = (unsigned short*)(ws);                 //  64 MB
  unsigned short* ET   = (unsigned short*)(ws + 64 * MB);       //  64 MB
  unsigned short* qT   = (unsigned short*)(ws + 128 * MB);      //  32 MB
  unsigned short* aT   = (unsigned short*)(ws + 160 * MB);      //  32 MB
  unsigned short* qb16 = (unsigned short*)(ws + 192 * MB);      //  32 MB
  unsigned short* ab16 = (unsigned short*)(ws + 224 * MB);      //  32 MB
  float* sums = (float*)(ws + 256 * MB);                        // 256 KB (row|col)
  float* qsum = (float*)(ws + 256 * MB + (256 << 10));          //  64 KB
  float* asum = (float*)(ws + 256 * MB + (320 << 10));          //  64 KB

  void* args[] = { (void*)&q, (void*)&a, (void*)&qm, (void*)&am, (void*)&temp,
                   (void*)&out0, (void*)&out1,
                   (void*)&E, (void*)&ET, (void*)&qT, (void*)&aT,
                   (void*)&qb16, (void*)&ab16,
                   (void*)&sums, (void*)&qsum, (void*)&asum };
  hipLaunchCooperativeKernel((void*)k_mega, dim3(256), dim3(512), args, 0, stream);
}

// Round 5
// 592.174 us; speedup vs baseline: 1.2276x; 1.2276x over previous
//
#include <hip/hip_runtime.h>
#include <cstdint>
#include <cstddef>

// Problem constants: B=32, LQ=LA=1024, H=512
#define NB   32
#define LQA  1024   // LQ == LA
#define HD   512

typedef __attribute__((ext_vector_type(4))) float  f32x4;
typedef __attribute__((ext_vector_type(8))) short  s16x8;   // 8 bf16 (4 VGPRs) MFMA frag
typedef __attribute__((ext_vector_type(4))) unsigned short u16x4;

static __device__ __forceinline__ unsigned short f2bf(float f) {
  unsigned int u = __builtin_bit_cast(unsigned int, f);
  u += 0x7fffu + ((u >> 16) & 1u);      // RNE
  return (unsigned short)(u >> 16);
}
static __device__ __forceinline__ float bf2f(unsigned short h) {
  unsigned int u = ((unsigned int)h) << 16;
  return __builtin_bit_cast(float, u);
}
static __device__ __forceinline__ u16x4 cvt4(f32x4 v) {
  u16x4 r;
  r.x = f2bf(v.x); r.y = f2bf(v.y); r.z = f2bf(v.z); r.w = f2bf(v.w);
  return r;
}

// async global->LDS, 16B per lane; lds base must be wave-uniform (HW scatters
// lane i at base + i*16)
typedef __attribute__((address_space(1))) const void gas_void;
typedef __attribute__((address_space(3))) void las_void;
static __device__ __forceinline__ void gload_lds16(const void* g, void* l) {
  __builtin_amdgcn_global_load_lds((gas_void*)g, (las_void*)l, 16, 0, 0);
}

// ---------------------------------------------------------------------------
// K0 (fused for q and a): per-batch 64x64 tiled, fp32 [LQA x HD] ->
//   (a) fp32 copy into concat-output left half,
//   (b) bf16 transposed copy [HD x LQA]  (aggregation-GEMM B operands),
//   (c) bf16 row-major copy [LQA x HD]   (score-GEMM operands),
//   (d) fused per-h column sums (sum over q/a of bf16 values) via atomics.
// grid: (HD/64=8, LQA/64=16, 2*NB), block 256
// ---------------------------------------------------------------------------
__global__ __launch_bounds__(256) void k_prep(
    const float* __restrict__ qsrc, const float* __restrict__ asrc,
    float* __restrict__ out0, float* __restrict__ out1,
    unsigned short* __restrict__ qT, unsigned short* __restrict__ aT,
    unsigned short* __restrict__ qb16, unsigned short* __restrict__ ab16,
    float* __restrict__ qsum, float* __restrict__ asum)   // [NB*HD], pre-zeroed
{
  const int bz  = blockIdx.z;
  const int isA = bz >> 5;           // 0: q-matrix, 1: a-matrix
  const int b   = bz & 31;
  const int h0 = blockIdx.x * 64;
  const int q0 = blockIdx.y * 64;
  const int t  = threadIdx.x;

  const float* src = isA ? asrc : qsrc;
  float* out_left      = isA ? out1 : out0;
  unsigned short* dstT = isA ? aT : qT;
  unsigned short* dstN = isA ? ab16 : qb16;
  float* csum          = isA ? asum : qsum;

  __shared__ unsigned short T[64 * 68];

  const float* sb = src + (size_t)b * LQA * HD;
  float* ob       = out_left + (size_t)b * LQA * 1024;
  unsigned short* db  = dstT + (size_t)b * HD * LQA;
  unsigned short* dbn = dstN + (size_t)b * LQA * HD;

#pragma unroll
  for (int j = 0; j < 4; ++j) {
    int f = t + 256 * j;
    int r = f >> 4;            // 0..63 (q-local)
    int c = (f & 15) * 4;      // 0..60 (h-local)
    f32x4 v = *(const f32x4*)(sb + (size_t)(q0 + r) * HD + h0 + c);
    *(f32x4*)(ob + (size_t)(q0 + r) * 1024 + h0 + c) = v;   // concat left half
    u16x4 cv = cvt4(v);
    *(u16x4*)&dbn[(size_t)(q0 + r) * HD + h0 + c] = cv;     // row-major bf16
    *(u16x4*)&T[r * 68 + c] = cv;
  }
  __syncthreads();
#pragma unroll
  for (int j = 0; j < 4; ++j) {
    int f = t + 256 * j;
    int orow = f >> 4;         // 0..63 (h-local); 16 consecutive lanes share it
    int c = (f & 15) * 4;      // 0..60 (q-local)
    u16x4 v;
    v.x = T[(c + 0) * 68 + orow];
    v.y = T[(c + 1) * 68 + orow];
    v.z = T[(c + 2) * 68 + orow];
    v.w = T[(c + 3) * 68 + orow];
    *(u16x4*)&db[(size_t)(h0 + orow) * LQA + q0 + c] = v;
    // fused column sum: this 16-lane group covers q-cols q0..q0+63 of row h
    float s = bf2f(v.x) + bf2f(v.y) + bf2f(v.z) + bf2f(v.w);
    s += __shfl_xor(s, 1); s += __shfl_xor(s, 2);
    s += __shfl_xor(s, 4); s += __shfl_xor(s, 8);
    if ((t & 15) == 0)
      atomicAdd(&csum[(size_t)b * HD + h0 + orow], s);
  }
}

// ---------------------------------------------------------------------------
// K1: scores. E[b,q,a] = qm*am*exp(temp * dot(q,a)); writes E and E^T (bf16),
// plus fused atomic row sums (over a) and col sums (over q) of E.
// 128x128 tile, BK=64, gload_lds(16B) staging.
// LDS tiles are XOR-swizzled (T2, rule #21): phys chunk = logical ^ (row&7).
// gload_lds writes linearly, so the SOURCE global chunk is inverse-swizzled
// and the frag-read applies the same XOR; both sides the same involution.
// Without this, [128][128B] rows are a 16-way bank conflict on ds_read_b128.
// grid: flat 2048 = 8 mt x 8 nt x NB, XCD-batch-locality swizzled; block 256.
// ---------------------------------------------------------------------------
__global__ __launch_bounds__(256) void k_scores(
    const unsigned short* __restrict__ qb16, const unsigned short* __restrict__ ab16,
    const int* __restrict__ qmask, const int* __restrict__ amask,
    const float* __restrict__ temp_p,
    unsigned short* __restrict__ E, unsigned short* __restrict__ ET,
    float* __restrict__ rowsumE,    // [NB*LQA], pre-zeroed; sum over a per (b,q)
    float* __restrict__ colsumE)    // [NB*LQA], pre-zeroed; sum over q per (b,a)
{
  const int flat = blockIdx.x;          // 0..2047
  const int xcd  = flat & 7;
  const int i5   = flat >> 3;           // 0..255
  const int b    = (i5 >> 6) * 8 + xcd; // 0..31
  const int tile = i5 & 63;
  const int m0 = (tile & 7) * 128;
  const int n0 = (tile >> 3) * 128;

  const int t  = threadIdx.x;
  const int lane = t & 63;
  const int w  = t >> 6;
  const int moff = (w & 1) * 64;
  const int noff = (w >> 1) * 64;
  const int lrow = lane & 15;
  const int quad = lane >> 4;
  const int xq   = lrow & 7;            // row&7 for every frag row (see below)

  // As/Bs ([128][64] = 16KB each) alias the epilogue Cs buffer (33.8KB)
  __shared__ __align__(16) unsigned short smem[128 * 132];
  unsigned short* As = smem;          // [128][64], chunk-swizzled
  unsigned short* Bs = smem + 8192;   // [128][64], chunk-swizzled

  const unsigned short* qb = qb16 + (size_t)b * LQA * HD;
  const unsigned short* ab = ab16 + (size_t)b * LQA * HD;

  // staging (BK=64): pass p, thread t -> phys chunk f=t+256p lands at LDS
  // short 8f (linear): row f>>3, phys chunk f&7. The data that belongs there
  // is LOGICAL chunk (f&7)^((f>>3)&7); 32p = 0 mod 8 so the XOR is p-invariant.
  const int sc = ((t & 7) ^ ((t >> 3) & 7)) * 8;
  const unsigned short* qg = qb + (size_t)(m0 + (t >> 3)) * HD + sc;
  const unsigned short* ag = ab + (size_t)(n0 + (t >> 3)) * HD + sc;

  f32x4 acc[4][4];
#pragma unroll
  for (int i = 0; i < 4; ++i)
#pragma unroll
    for (int j = 0; j < 4; ++j) acc[i][j] = (f32x4)0.f;

  for (int kt = 0; kt < HD / 64; ++kt) {
    const int ko = kt * 64;
#pragma unroll
    for (int p = 0; p < 4; ++p) {
      gload_lds16(qg + ko + p * 32 * HD, As + (w + 4 * p) * 512);
      gload_lds16(ag + ko + p * 32 * HD, Bs + (w + 4 * p) * 512);
    }
    __syncthreads();
#pragma unroll
    for (int ks = 0; ks < 2; ++ks) {
      s16x8 af[4], bfr[4];
#pragma unroll
      for (int i = 0; i < 4; ++i) {
        // logical chunk = ks*4+quad; phys = logical ^ (row&7), row&7 == lrow&7
        af[i]  = *(const s16x8*)&As[(moff + i * 16 + lrow) * 64 + ((ks * 4 + quad) ^ xq) * 8];
        bfr[i] = *(const s16x8*)&Bs[(noff + i * 16 + lrow) * 64 + ((ks * 4 + quad) ^ xq) * 8];
      }
#pragma unroll
      for (int i = 0; i < 4; ++i)
#pragma unroll
        for (int j = 0; j < 4; ++j)
          acc[i][j] = __builtin_amdgcn_mfma_f32_16x16x32_bf16(af[i], bfr[j], acc[i][j], 0, 0, 0);
    }
    __syncthreads();
  }

  // Epilogue: temp/mask/exp -> Cs (bf16), partial sums, then E / E^T writes.
  unsigned short* Cs = smem;   // [128][132], safe after final barrier
  const float temp = temp_p[0];
  const int* qmb = qmask + b * LQA;
  const int* amb = amask + b * LQA;

  float rowp[4][4];            // [i][r] partial row sums (this thread's 4 cols)
  float colp[4];               // [j]    partial col sums (this thread's 16 rows)
#pragma unroll
  for (int i = 0; i < 4; ++i)
#pragma unroll
    for (int r = 0; r < 4; ++r) rowp[i][r] = 0.f;
#pragma unroll
  for (int j = 0; j < 4; ++j) colp[j] = 0.f;

#pragma unroll
  for (int i = 0; i < 4; ++i) {
#pragma unroll
    for (int j = 0; j < 4; ++j) {
      int ncol = noff + j * 16 + lrow;
      float am = (amb[n0 + ncol] != 0) ? 1.f : 0.f;
#pragma unroll
      for (int r = 0; r < 4; ++r) {
        int mrow = moff + i * 16 + quad * 4 + r;
        float qm = (qmb[m0 + mrow] != 0) ? 1.f : 0.f;
        float e = __expf(acc[i][j][r] * temp) * am * qm;
        unsigned short eb = f2bf(e);
        float er = bf2f(eb);               // sum the ROUNDED value (matches E)
        Cs[mrow * 132 + ncol] = eb;
        rowp[i][r] += er;
        colp[j] += er;
      }
    }
  }

  // row sums: 16-lane butterfly, one atomic per row per wave.
#pragma unroll
  for (int i = 0; i < 4; ++i)
#pragma unroll
    for (int r = 0; r < 4; ++r) {
      float v = rowp[i][r];
      v += __shfl_xor(v, 1); v += __shfl_xor(v, 2);
      v += __shfl_xor(v, 4); v += __shfl_xor(v, 8);
      if (lrow == 0)
        atomicAdd(&rowsumE[(size_t)b * LQA + m0 + moff + i * 16 + quad * 4 + r], v);
    }
  // col sums: quads 0..3 hold disjoint 16-row partials of the same col.
#pragma unroll
  for (int j = 0; j < 4; ++j) {
    float v = colp[j];
    v += __shfl_xor(v, 16); v += __shfl_xor(v, 32);
    if (quad == 0)
      atomicAdd(&colsumE[(size_t)b * LQA + n0 + noff + j * 16 + lrow], v);
  }

  __syncthreads();
  const size_t Ebase = (size_t)b * LQA * LQA;
#pragma unroll
  for (int jj = 0; jj < 16; ++jj) {
    int f = t + 256 * jj;
    int row = f >> 5;            // 0..127
    int c = (f & 31) * 4;        // 0..124
    u16x4 v = *(const u16x4*)&Cs[row * 132 + c];
    *(u16x4*)&E[Ebase + (size_t)(m0 + row) * LQA + n0 + c] = v;
  }
#pragma unroll
  for (int jj = 0; jj < 16; ++jj) {
    int f = t + 256 * jj;
    int orow = f >> 5;           // a-local
    int c = (f & 31) * 4;        // q-local
    u16x4 v;
    v.x = Cs[(c + 0) * 132 + orow];
    v.y = Cs[(c + 1) * 132 + orow];
    v.z = Cs[(c + 2) * 132 + orow];
    v.w = Cs[(c + 3) * 132 + orow];
    *(u16x4*)&ET[Ebase + (size_t)(n0 + orow) * LQA + m0 + c] = v;
  }
}

// ---------------------------------------------------------------------------
// K3: aggregation GEMMs, full-output-width blocks (BM=128, BN=512=HD, BK=32).
//   half 0: out0[b,m,512+n] = f(rowsumE) . (E @ aT)   (+ asum term)
//   half 1: out1[b,m,512+n] = f(colsumE) . (ET @ qT)  (+ qsum term)
// BN=512 => each E/ET row-block is read EXACTLY ONCE; aT/qT panel fits L2.
// 8 waves (512 thr), wave tile 64x128. 1 block/CU (120 KB LDS), 3-deep
// pipeline with counted vmcnt (never 0 in-loop).
// LDS tiles XOR-swizzled (T2, rule #21): phys chunk = logical ^ ((row>>1)&3);
// staging source inverse-swizzled, frag reads apply the same XOR (the
// unswizzled [row][64B] layout is a ~4-way ds_read_b128 conflict).
// grid: flat 512 = 2 halves x 8 mt x NB, XCD-swizzled; block 512.
// ---------------------------------------------------------------------------
__global__ __launch_bounds__(512, 2) void k_agg2(
    const unsigned short* __restrict__ Ein,
    const unsigned short* __restrict__ ETin,
    const unsigned short* __restrict__ qT,
    const unsigned short* __restrict__ aT,
    const float* __restrict__ sums,     // [2][NB*LQA]: rowsumE | colsumE
    const float* __restrict__ qsum,     // [NB*HD]
    const float* __restrict__ asum,     // [NB*HD]
    float* __restrict__ out0, float* __restrict__ out1)
{
  // XCD swizzle: physical blk%8 = xcd (heuristic); logical id contiguous per
  // XCD so each XCD works through whole (half,batch) groups (8 m-blocks each).
  const int blk  = blockIdx.x;                 // 0..511
  const int L    = (blk & 7) * 64 + (blk >> 3);
  const int half = L >> 8;                     // 0..1
  const int rem  = L & 255;
  const int b    = rem >> 3;                   // 0..31
  const int m0   = (rem & 7) * 128;

  const unsigned short* Emat = half ? ETin : Ein;
  const unsigned short* Bt   = half ? qT : aT;
  const float* srow = sums + (size_t)half * NB * LQA + (size_t)b * LQA;
  const float* bsp  = (half ? qsum : asum) + (size_t)b * HD;
  float* ob = (half ? out1 : out0) + (size_t)b * LQA * 1024;

  const int t    = threadIdx.x;                // 0..511
  const int lane = t & 63;
  const int w    = t >> 6;                     // wave 0..7
  const int wr   = w >> 2;                     // 0..1 (m-dir)
  const int wc   = w & 3;                      // 0..3 (n-dir)
  const int lrow = lane & 15;
  const int quad = lane >> 4;
  const int xa   = (lrow >> 1) & 3;            // (row>>1)&3 for every frag row

  // 3 buffers x (A[128][32] = 4096 + B[512][32] = 16384 shorts) = 120 KB
  __shared__ __align__(16) unsigned short lds[3 * 20480];

  const unsigned short* Eb = Emat + (size_t)b * LQA * LQA;
  const unsigned short* Bb = Bt + (size_t)b * HD * LQA;

  // staging: phys chunk f -> LDS short 8f: row f>>2, phys chunk f&3; fetch
  // LOGICAL chunk (f&3)^((f>>3)&3). For B, f = t+512p: (f>>3)&3 is p-invariant.
  const int scA = ((t & 3) ^ ((t >> 3) & 3)) * 8;
  const unsigned short* agp = Eb + (size_t)(m0 + (t >> 2)) * LQA + scA;
  const unsigned short* bgp[4];
#pragma unroll
  for (int p = 0; p < 4; ++p)
    bgp[p] = Bb + (size_t)(128 * p + (t >> 2)) * LQA + scA;
  const int ldsA = w * 512;            // + lane*8 via HW scatter
  const int ldsB = 4096 + w * 512;     // + p*4096

#define STAGE(kt, buf)                                                     \
  do {                                                                     \
    unsigned short* bp_ = lds + (buf) * 20480;                             \
    const int ko_ = (kt) * 32;                                             \
    gload_lds16(agp + ko_, bp_ + ldsA);                                    \
    gload_lds16(bgp[0] + ko_, bp_ + ldsB);                                 \
    gload_lds16(bgp[1] + ko_, bp_ + ldsB + 4096);                          \
    gload_lds16(bgp[2] + ko_, bp_ + ldsB + 8192);                          \
    gload_lds16(bgp[3] + ko_, bp_ + ldsB + 12288);                         \
  } while (0)

  f32x4 acc[4][8];
#pragma unroll
  for (int i = 0; i < 4; ++i)
#pragma unroll
    for (int j = 0; j < 8; ++j) acc[i][j] = (f32x4)0.f;

  STAGE(0, 0); STAGE(1, 1); STAGE(2, 2);   // 15 vm-instructions in flight

  int cur = 0;
  for (int k = 0; k < 32; ++k) {
    // own tile-k loads complete (5 instr/tile; up to 2 future tiles stay
    // in flight); barrier makes every wave's slice visible.
    if (k <= 29)      asm volatile("s_waitcnt vmcnt(10)");
    else if (k == 30) asm volatile("s_waitcnt vmcnt(5)");
    else              asm volatile("s_waitcnt vmcnt(0)");
    __builtin_amdgcn_sched_barrier(0);
    __builtin_amdgcn_s_barrier();
    __builtin_amdgcn_sched_barrier(0);

    const unsigned short* As = lds + cur * 20480;
    const unsigned short* Bs = As + 4096;
    s16x8 bfr[8];
#pragma unroll
    for (int j = 0; j < 8; ++j)
      bfr[j] = *(const s16x8*)&Bs[(wc * 128 + j * 16 + lrow) * 32 + (quad ^ xa) * 8];
#pragma unroll
    for (int i = 0; i < 4; ++i) {
      s16x8 af = *(const s16x8*)&As[(wr * 64 + i * 16 + lrow) * 32 + (quad ^ xa) * 8];
#pragma unroll
      for (int j = 0; j < 8; ++j)
        acc[i][j] = __builtin_amdgcn_mfma_f32_16x16x32_bf16(af, bfr[j], acc[i][j], 0, 0, 0);
    }

    // release buffer: own LDS reads retired, then barrier, then overwrite.
    asm volatile("s_waitcnt lgkmcnt(0)");
    __builtin_amdgcn_sched_barrier(0);
    __builtin_amdgcn_s_barrier();
    if (k + 3 < 32) STAGE(k + 3, cur);
    cur = (cur == 2) ? 0 : cur + 1;
  }
#undef STAGE

  // Epilogue: inline stats (inv/add from raw sum) + uniform-row term.
  float bcol[8];
#pragma unroll
  for (int j = 0; j < 8; ++j) bcol[j] = bsp[wc * 128 + j * 16 + lrow];
#pragma unroll
  for (int i = 0; i < 4; ++i) {
#pragma unroll
    for (int r = 0; r < 4; ++r) {
      int mrow = wr * 64 + i * 16 + quad * 4 + r;
      float s = srow[m0 + mrow];
      float inv = (s > 0.f) ? 1.f / s : 0.f;
      float add = (s > 0.f) ? 0.f : (1.f / 1024.f);
#pragma unroll
      for (int j = 0; j < 8; ++j) {
        int ncol = wc * 128 + j * 16 + lrow;
        ob[(size_t)(m0 + mrow) * 1024 + 512 + ncol] =
            inv * acc[i][j][r] + add * bcol[j];
      }
    }
  }
}

// ---------------------------------------------------------------------------
extern "C" void kernel_launch(void* const* d_in, const int* in_sizes, int n_in,
                              void* d_out, int out_size, void* d_ws, size_t ws_size,
                              hipStream_t stream) {
  (void)in_sizes; (void)n_in; (void)out_size; (void)ws_size;
  const float* q    = (const float*)d_in[0];
  const float* a    = (const float*)d_in[1];
  const int*   qm   = (const int*)d_in[2];
  const int*   am   = (const int*)d_in[3];
  const float* temp = (const float*)d_in[4];

  float* out0 = (float*)d_out;                         // [NB][LQA][1024] concat(q, q_s)
  float* out1 = out0 + (size_t)NB * LQA * 1024;        // [NB][LQA][1024] concat(a, a_s)

  char* ws = (char*)d_ws;
  const size_t MB = 1024ull * 1024ull;
  unsigned short* E    = (unsigned short*)(ws);                 //  64 MB
  unsigned short* ET   = (unsigned short*)(ws + 64 * MB);       //  64 MB
  unsigned short* qT   = (unsigned short*)(ws + 128 * MB);      //  32 MB
  unsigned short* aT   = (unsigned short*)(ws + 160 * MB);      //  32 MB
  unsigned short* qb16 = (unsigned short*)(ws + 192 * MB);      //  32 MB
  unsigned short* ab16 = (unsigned short*)(ws + 224 * MB);      //  32 MB
  float* sums = (float*)(ws + 256 * MB);                        // 256 KB (row|col)
  float* qsum = (float*)(ws + 256 * MB + (256 << 10));          //  64 KB
  float* asum = (float*)(ws + 256 * MB + (320 << 10));          //  64 KB

  // zero all atomic accumulators in one contiguous memset (384 KB)
  hipMemsetAsync(sums, 0, (size_t)(2 * NB * LQA + 2 * NB * HD) * sizeof(float), stream);
  k_prep<<<dim3(8, 16, 2 * NB), 256, 0, stream>>>(q, a, out0, out1, qT, aT,
                                                  qb16, ab16, qsum, asum);
  k_scores<<<dim3(2048), 256, 0, stream>>>(qb16, ab16, qm, am, temp,
                                           E, ET, sums, sums + NB * LQA);
  k_agg2<<<dim3(512), 512, 0, stream>>>(E, ET, qT, aT, sums, qsum, asum,
                                        out0, out1);
}